// Round 7
// baseline (150.957 us; speedup 1.0000x reference)
//
#include <hip/hip_runtime.h>
#include <hip/hip_fp16.h>

#define D 512
#define KT 64           // k-columns of E per tile (f16 tile = 512*64*2B = 64 KB LDS)
#define NT 8            // D / KT
#define LOG2E 1.44269504088896340736f

#if defined(__has_builtin)
#if __has_builtin(__builtin_amdgcn_exp2f)
#define EXP2(x) __builtin_amdgcn_exp2f(x)
#else
#define EXP2(x) exp2f(x)
#endif
#else
#define EXP2(x) exp2f(x)
#endif

union H2U { __half2 h; unsigned int u; };

__device__ __forceinline__ unsigned int pkh(float lo, float hi) {
  H2U p; p.h = __float22half2_rn(make_float2(lo, hi));
  return p.u;
}
__device__ __forceinline__ float2 uph(unsigned int u) {
  H2U p; p.u = u;
  return __half22float2(p.h);
}

// One block per batch row. Single-exp scheme with column max-shift:
//   M_k  = a_k * (a_k > 0 ? max(b) : min(b))          (true column max of b_j*a_k)
//   E[j,k] = exp(b_j*a_k - M_k)  <= 1   -> f16-safe, computed ONCE
//   Z'_k = sum_j E[j,k]  (f32, from unrounded values)
//   attn[j] = sum_k (a_k / Z'_k) * E[j,k]             (shift cancels exactly)
// E granule swizzle: 16B granule g of row j stored at g ^ (j&7) -> both the
// write wave (j&7 = lane>>3) and read wave (j&7 = lane&7) cover all 32 banks
// per 8-lane group.
__global__ __launch_bounds__(256, 2) void attn_kernel(
    const float* __restrict__ a, const float* __restrict__ b,
    float* __restrict__ attn) {
  __shared__ unsigned int E[D * KT / 2];  // 64 KB, f16 pairs
  __shared__ float a_s[D];                // 2 KB
  __shared__ float zred[32 * 68];         // 8.7 KB, [jp][k] partials
  __shared__ float c_s[KT];               // 256 B
  __shared__ float red[8];

  const int bt = blockIdx.x;
  const int tid = threadIdx.x;
  const float* __restrict__ ap = a + (size_t)bt * D;
  const float* __restrict__ bp = b + (size_t)bt * D;

  {  // stage a row
    float2 va = *(const float2*)(ap + tid * 2);
    a_s[tid * 2] = va.x;
    a_s[tid * 2 + 1] = va.y;
  }

  const int k8 = tid & 7;   // owns k-granule k8 (8 k's)
  const int jp = tid >> 3;  // 0..31, owns rows j === jp (mod 32)

  // b values this thread ever needs (j = jj*32 + jp) -> registers, loaded once
  float breg[16];
#pragma unroll
  for (int jj = 0; jj < 16; ++jj) breg[jj] = bp[jj * 32 + jp];

  // block-wide max/min of b (for the column shift M_k)
  float bmax = breg[0], bmin = breg[0];
#pragma unroll
  for (int jj = 1; jj < 16; ++jj) {
    bmax = fmaxf(bmax, breg[jj]);
    bmin = fminf(bmin, breg[jj]);
  }
#pragma unroll
  for (int off = 32; off; off >>= 1) {
    bmax = fmaxf(bmax, __shfl_xor(bmax, off));
    bmin = fminf(bmin, __shfl_xor(bmin, off));
  }
  if ((tid & 63) == 0) {
    red[tid >> 6] = bmax;
    red[4 + (tid >> 6)] = bmin;
  }
  __syncthreads();
  bmax = fmaxf(fmaxf(red[0], red[1]), fmaxf(red[2], red[3]));
  bmin = fminf(fminf(red[4], red[5]), fminf(red[6], red[7]));

  float at0a = 0.f, at0b = 0.f, at1a = 0.f, at1b = 0.f;
  const int jr0 = tid;        // pass-2 row 0
  const int jr1 = tid + 256;  // pass-2 row 1 (same &7)
  const int sw = jr0 & 7;

  for (int t = 0; t < NT; ++t) {
    const int k0 = t * KT;
    float alk[8], m2[8];
#pragma unroll
    for (int c = 0; c < 8; ++c) {
      const float ar = a_s[k0 + k8 * 8 + c];
      const float al = ar * LOG2E;
      alk[c] = al;
      m2[c] = -al * (ar > 0.f ? bmax : bmin);  // -M_k * log2e
    }
    float z0 = 0.f, z1 = 0.f, z2 = 0.f, z3 = 0.f;
    float z4 = 0.f, z5 = 0.f, z6 = 0.f, z7 = 0.f;

    // ---- pass 1: 16 rows x 8 k per thread, exp once, Z in f32, E -> f16 LDS
#pragma unroll
    for (int jj = 0; jj < 16; ++jj) {
      const int j = jj * 32 + jp;
      const float bj = breg[jj];
      const float e0 = EXP2(fmaf(alk[0], bj, m2[0]));
      const float e1 = EXP2(fmaf(alk[1], bj, m2[1]));
      const float e2 = EXP2(fmaf(alk[2], bj, m2[2]));
      const float e3 = EXP2(fmaf(alk[3], bj, m2[3]));
      const float e4 = EXP2(fmaf(alk[4], bj, m2[4]));
      const float e5 = EXP2(fmaf(alk[5], bj, m2[5]));
      const float e6 = EXP2(fmaf(alk[6], bj, m2[6]));
      const float e7 = EXP2(fmaf(alk[7], bj, m2[7]));
      z0 += e0; z1 += e1; z2 += e2; z3 += e3;
      z4 += e4; z5 += e5; z6 += e6; z7 += e7;
      uint4 u;
      u.x = pkh(e0, e1);
      u.y = pkh(e2, e3);
      u.z = pkh(e4, e5);
      u.w = pkh(e6, e7);
      *((uint4*)((char*)E + j * 128 + ((k8 ^ (j & 7)) * 16))) = u;
    }
    {  // partial Z to LDS
      float* zp = &zred[jp * 68 + k8 * 8];
      *(float4*)zp = make_float4(z0, z1, z2, z3);
      *(float4*)(zp + 4) = make_float4(z4, z5, z6, z7);
    }
    __syncthreads();
    if (tid < KT) {  // finalize: c_k = a_k / Z'_k  (2-way bank access, free)
      float Z = 0.f;
#pragma unroll
      for (int p = 0; p < 32; ++p) Z += zred[p * 68 + tid];
      c_s[tid] = a_s[k0 + tid] / Z;
    }
    __syncthreads();

    // ---- pass 2: two rows per thread, E read back (f16 -> f32), fma with c
#pragma unroll
    for (int g = 0; g < 8; ++g) {
      const float4 c0 = *(const float4*)&c_s[g * 8];      // broadcast
      const float4 c1 = *(const float4*)&c_s[g * 8 + 4];  // broadcast
      const int pg = (g ^ sw) * 16;
      const uint4 u0 = *(const uint4*)((const char*)E + jr0 * 128 + pg);
      const uint4 u1 = *(const uint4*)((const char*)E + jr1 * 128 + pg);
      float2 f;
      f = uph(u0.x); at0a = fmaf(f.x, c0.x, at0a); at0b = fmaf(f.y, c0.y, at0b);
      f = uph(u0.y); at0a = fmaf(f.x, c0.z, at0a); at0b = fmaf(f.y, c0.w, at0b);
      f = uph(u0.z); at0a = fmaf(f.x, c1.x, at0a); at0b = fmaf(f.y, c1.y, at0b);
      f = uph(u0.w); at0a = fmaf(f.x, c1.z, at0a); at0b = fmaf(f.y, c1.w, at0b);
      f = uph(u1.x); at1a = fmaf(f.x, c0.x, at1a); at1b = fmaf(f.y, c0.y, at1b);
      f = uph(u1.y); at1a = fmaf(f.x, c0.z, at1a); at1b = fmaf(f.y, c0.w, at1b);
      f = uph(u1.z); at1a = fmaf(f.x, c1.x, at1a); at1b = fmaf(f.y, c1.y, at1b);
      f = uph(u1.w); at1a = fmaf(f.x, c1.z, at1a); at1b = fmaf(f.y, c1.w, at1b);
    }
    __syncthreads();  // E reused next tile
  }
  attn[(size_t)bt * D + jr0] = at0a + at0b;
  attn[(size_t)bt * D + jr1] = at1a + at1b;
}

// out = a + bias. out has B*D/4 = 131072 float4s -> 512 blocks x 256 threads.
__global__ __launch_bounds__(256) void init_out(const float* __restrict__ a,
                                                const float* __restrict__ bias,
                                                float* __restrict__ out) {
  const int g = blockIdx.x * 256 + threadIdx.x;  // float4 index, 512 blocks
  const float4 av = ((const float4*)a)[g];
  const float4 bv = ((const float4*)bias)[g & 127];
  float4 o;
  o.x = av.x + bv.x;
  o.y = av.y + bv.y;
  o.z = av.z + bv.z;
  o.w = av.w + bv.w;
  ((float4*)out)[g] = o;
}

// out += attn @ W^T, 64x64 tile, BK=32, 4-way K-split (grid.z), f32 atomics.
__global__ __launch_bounds__(256) void gemm_kernel(
    const float* __restrict__ attn, const float* __restrict__ W,
    float* __restrict__ out) {
  __shared__ float As[32][68];
  __shared__ float Bs[32][68];
  const int tid = threadIdx.x;
  const int bx = blockIdx.x;  // 0..7  N tiles
  const int by = blockIdx.y;  // 0..15 M tiles
  const int bz = blockIdx.z;  // 0..3  K chunks of 128
  const int tx = tid & 15;
  const int ty = tid >> 4;
  float acc[4][4] = {};

  const int kbeg = bz * 128;
  for (int k0 = kbeg; k0 < kbeg + 128; k0 += 32) {
#pragma unroll
    for (int xx = 0; xx < 2; ++xx) {
      const int x = tid + xx * 256;
      const int r = x >> 3;
      const int c4 = x & 7;
      const float4 va =
          *(const float4*)(attn + (size_t)(by * 64 + r) * D + k0 + c4 * 4);
      const float4 vw =
          *(const float4*)(W + (size_t)(bx * 64 + r) * D + k0 + c4 * 4);
      As[c4 * 4 + 0][r] = va.x;
      As[c4 * 4 + 1][r] = va.y;
      As[c4 * 4 + 2][r] = va.z;
      As[c4 * 4 + 3][r] = va.w;
      Bs[c4 * 4 + 0][r] = vw.x;
      Bs[c4 * 4 + 1][r] = vw.y;
      Bs[c4 * 4 + 2][r] = vw.z;
      Bs[c4 * 4 + 3][r] = vw.w;
    }
    __syncthreads();
#pragma unroll
    for (int kk = 0; kk < 32; ++kk) {
      const float4 af = *(const float4*)&As[kk][ty * 4];
      const float4 bf = *(const float4*)&Bs[kk][tx * 4];
      const float afv[4] = {af.x, af.y, af.z, af.w};
      const float bfv[4] = {bf.x, bf.y, bf.z, bf.w};
#pragma unroll
      for (int i = 0; i < 4; ++i)
#pragma unroll
        for (int j = 0; j < 4; ++j) acc[i][j] = fmaf(afv[i], bfv[j], acc[i][j]);
    }
    __syncthreads();
  }

  const int n = bx * 64 + tx * 4;
#pragma unroll
  for (int i = 0; i < 4; ++i) {
    float* op = out + (size_t)(by * 64 + ty * 4 + i) * D + n;
    atomicAdd(op + 0, acc[i][0]);
    atomicAdd(op + 1, acc[i][1]);
    atomicAdd(op + 2, acc[i][2]);
    atomicAdd(op + 3, acc[i][3]);
  }
}

extern "C" void kernel_launch(void* const* d_in, const int* in_sizes, int n_in,
                              void* d_out, int out_size, void* d_ws,
                              size_t ws_size, hipStream_t stream) {
  const float* a = (const float*)d_in[0];
  const float* b = (const float*)d_in[1];
  const float* W = (const float*)d_in[2];
  const float* bias = (const float*)d_in[3];
  float* out = (float*)d_out;
  float* attn = (float*)d_ws;  // 2 MB scratch

  init_out<<<512, 256, 0, stream>>>(a, bias, out);
  attn_kernel<<<1024, 256, 0, stream>>>(a, b, attn);
  gemm_kernel<<<dim3(8, 16, 4), 256, 0, stream>>>(attn, W, out);
}

// Round 11
// 128.740 us; speedup vs baseline: 1.1726x; 1.1726x over previous
//
#include <hip/hip_runtime.h>

#define D 512
#define KT 64
#define NT 8
#define LOG2E 1.44269504088896340736f

#if defined(__has_builtin)
#if __has_builtin(__builtin_amdgcn_exp2f)
#define EXP2(x) __builtin_amdgcn_exp2f(x)
#else
#define EXP2(x) exp2f(x)
#endif
#else
#define EXP2(x) exp2f(x)
#endif

// One block per batch row. E kept entirely in REGISTERS (f32):
//   thread (jp = tid>>3, k8 = tid&7) owns rows j = jj*32+jp (16 of them) and
//   k-slots k = k0 + k8*8 + c (8 of them) of each 64-wide k-tile.
//   pass1: e[jj][c] = exp2(a_k*b_j*log2e)  (128 regs), z[c] partial sums
//   zred LDS reduce -> c_s[k] = a_k / Z_k
//   pass2: part[jj] += c_s[k] * e[jj][c]   (all from regs)
// Final: 3-step shfl_xor reduce over the 8 k8-lanes; coalesced write via LDS.
// No LDS E tile -> no 8-way b128 bank conflicts, no f16 rounding.
__global__ __launch_bounds__(256, 2) void attn_kernel(
    const float* __restrict__ a, const float* __restrict__ b,
    float* __restrict__ attn) {
  __shared__ float a_s[D];         // 2 KB
  __shared__ float zred[32 * 68];  // 8.7 KB [jp][k] partials (pad 68)
  __shared__ float c_s[KT];        // 256 B
  __shared__ float attn_s[D];      // 2 KB (output redistribution)

  const int bt = blockIdx.x;
  const int tid = threadIdx.x;
  const float* __restrict__ ap = a + (size_t)bt * D;
  const float* __restrict__ bp = b + (size_t)bt * D;

  {  // stage a row
    float2 va = *(const float2*)(ap + tid * 2);
    a_s[tid * 2] = va.x;
    a_s[tid * 2 + 1] = va.y;
  }

  const int k8 = tid & 7;   // k-granule (8 k's per tile)
  const int jp = tid >> 3;  // 0..31, rows j === jp (mod 32)

  float breg[16];
#pragma unroll
  for (int jj = 0; jj < 16; ++jj) breg[jj] = bp[jj * 32 + jp];

  float part[16];
#pragma unroll
  for (int jj = 0; jj < 16; ++jj) part[jj] = 0.f;

  __syncthreads();

  for (int t = 0; t < NT; ++t) {
    const int k0 = t * KT;
    float alk[8];
#pragma unroll
    for (int c = 0; c < 8; ++c) alk[c] = a_s[k0 + k8 * 8 + c] * LOG2E;

    float e[16][8];
    float z[8];
#pragma unroll
    for (int c = 0; c < 8; ++c) z[c] = 0.f;

    // ---- pass 1: 128 exps into registers, z partials in f32
#pragma unroll
    for (int jj = 0; jj < 16; ++jj) {
      const float bj = breg[jj];
#pragma unroll
      for (int c = 0; c < 8; ++c) {
        const float ev = EXP2(alk[c] * bj);
        e[jj][c] = ev;
        z[c] += ev;
      }
    }
    {  // partial Z to LDS (2-way bank access, free)
      float* zp = &zred[jp * 68 + k8 * 8];
      *(float4*)zp = make_float4(z[0], z[1], z[2], z[3]);
      *(float4*)(zp + 4) = make_float4(z[4], z[5], z[6], z[7]);
    }
    __syncthreads();
    if (tid < KT) {  // finalize: c_k = a_k / Z_k
      float Z = 0.f;
#pragma unroll
      for (int p = 0; p < 32; ++p) Z += zred[p * 68 + tid];
      c_s[tid] = a_s[k0 + tid] / Z;
    }
    __syncthreads();

    // ---- pass 2: register fma, no LDS E traffic
    float cs[8];
    *(float4*)&cs[0] = *(const float4*)&c_s[k8 * 8];
    *(float4*)&cs[4] = *(const float4*)&c_s[k8 * 8 + 4];
#pragma unroll
    for (int jj = 0; jj < 16; ++jj) {
#pragma unroll
      for (int c = 0; c < 8; ++c) part[jj] = fmaf(cs[c], e[jj][c], part[jj]);
    }
    // 2 barriers per tile suffice: zred writes of tile t+1 happen only after
    // barrier 2, which is after all finalize reads of tile t.
  }

  // reduce over the 8 k8-lanes (consecutive lanes, xor 1/2/4)
#pragma unroll
  for (int jj = 0; jj < 16; ++jj) {
    float v = part[jj];
    v += __shfl_xor(v, 1);
    v += __shfl_xor(v, 2);
    v += __shfl_xor(v, 4);
    part[jj] = v;
  }
  if (k8 == 0) {
#pragma unroll
    for (int jj = 0; jj < 16; ++jj) attn_s[jj * 32 + jp] = part[jj];
  }
  __syncthreads();
  {  // coalesced float2 store
    float2 v = *(const float2*)&attn_s[tid * 2];
    *(float2*)(attn + (size_t)bt * D + tid * 2) = v;
  }
}

// out = a + attn @ W^T + bias. Full K (no split, no atomics), 32x32 tile,
// BK=64, 2x2 micro-tile, 512 blocks (2/CU). Bias+residual fused in epilogue.
__global__ __launch_bounds__(256) void gemm_kernel(
    const float* __restrict__ attn, const float* __restrict__ W,
    const float* __restrict__ a, const float* __restrict__ bias,
    float* __restrict__ out) {
  __shared__ float As[64][36];  // [k][m], +4 pad
  __shared__ float Bs[64][36];  // [k][n]
  const int tid = threadIdx.x;
  const int bx = blockIdx.x;  // 0..15  N tiles
  const int by = blockIdx.y;  // 0..31  M tiles
  const int tx = tid & 15;
  const int ty = tid >> 4;
  const int r = tid >> 3;        // 0..31 staging row
  const int c0 = (tid & 7) * 8;  // 0..56 staging k-offset
  float acc[2][2] = {};

  for (int k0 = 0; k0 < D; k0 += 64) {
    const float4 va0 = *(const float4*)(attn + (size_t)(by * 32 + r) * D + k0 + c0);
    const float4 va1 = *(const float4*)(attn + (size_t)(by * 32 + r) * D + k0 + c0 + 4);
    const float4 vw0 = *(const float4*)(W + (size_t)(bx * 32 + r) * D + k0 + c0);
    const float4 vw1 = *(const float4*)(W + (size_t)(bx * 32 + r) * D + k0 + c0 + 4);
    As[c0 + 0][r] = va0.x; As[c0 + 1][r] = va0.y;
    As[c0 + 2][r] = va0.z; As[c0 + 3][r] = va0.w;
    As[c0 + 4][r] = va1.x; As[c0 + 5][r] = va1.y;
    As[c0 + 6][r] = va1.z; As[c0 + 7][r] = va1.w;
    Bs[c0 + 0][r] = vw0.x; Bs[c0 + 1][r] = vw0.y;
    Bs[c0 + 2][r] = vw0.z; Bs[c0 + 3][r] = vw0.w;
    Bs[c0 + 4][r] = vw1.x; Bs[c0 + 5][r] = vw1.y;
    Bs[c0 + 6][r] = vw1.z; Bs[c0 + 7][r] = vw1.w;
    __syncthreads();
#pragma unroll 16
    for (int kk = 0; kk < 64; ++kk) {
      const float2 af = *(const float2*)&As[kk][ty * 2];
      const float2 bf = *(const float2*)&Bs[kk][tx * 2];
      acc[0][0] = fmaf(af.x, bf.x, acc[0][0]);
      acc[0][1] = fmaf(af.x, bf.y, acc[0][1]);
      acc[1][0] = fmaf(af.y, bf.x, acc[1][0]);
      acc[1][1] = fmaf(af.y, bf.y, acc[1][1]);
    }
    __syncthreads();
  }

  const int m0 = by * 32 + ty * 2;
  const int n0 = bx * 32 + tx * 2;
  const float2 bv = *(const float2*)&bias[n0];
#pragma unroll
  for (int i = 0; i < 2; ++i) {
    const float2 av = *(const float2*)&a[(size_t)(m0 + i) * D + n0];
    float2 o;
    o.x = av.x + acc[i][0] + bv.x;
    o.y = av.y + acc[i][1] + bv.y;
    *(float2*)(out + (size_t)(m0 + i) * D + n0) = o;
  }
}

extern "C" void kernel_launch(void* const* d_in, const int* in_sizes, int n_in,
                              void* d_out, int out_size, void* d_ws,
                              size_t ws_size, hipStream_t stream) {
  const float* a = (const float*)d_in[0];
  const float* b = (const float*)d_in[1];
  const float* W = (const float*)d_in[2];
  const float* bias = (const float*)d_in[3];
  float* out = (float*)d_out;
  float* attn = (float*)d_ws;  // 2 MB scratch

  attn_kernel<<<1024, 256, 0, stream>>>(a, b, attn);
  gemm_kernel<<<dim3(16, 32), 256, 0, stream>>>(attn, W, a, bias, out);
}